// Round 2
// baseline (157.988 us; speedup 1.0000x reference)
//
#include <hip/hip_runtime.h>
#include <math.h>

#define DD 256

typedef float  f32x4  __attribute__((ext_vector_type(4)));
typedef short  bf16x8 __attribute__((ext_vector_type(8)));

__device__ __forceinline__ unsigned short f2bf(float f) {
    unsigned int u = __float_as_uint(f);
    u = (u + 0x7fffu + ((u >> 16) & 1u)) >> 16;  // RNE
    return (unsigned short)u;
}
__device__ __forceinline__ float bf2f(unsigned int h16) {
    return __uint_as_float(h16 << 16);
}

// ---------------------------------------------------------------------------
// Fused prep: blocks [0,192) repack weights fp32->bf16 into MFMA-fragment-
// linear order:
//   wall[mat][wb][k0][nt][lane] : 16 B holding
//   W_bt[n = wb*64 + nt*16 + (lane&15)][k = k0*32 + (lane>>4)*8 .. +8]
// Blocks 192,193 compute the universal-layer p vectors (uniform state is
// preserved by the circulant update -> s0 = 0.0625*prod cos; verified R1/R2
// of the original session).
// ---------------------------------------------------------------------------
__global__ __launch_bounds__(256)
void prep_all(const float* __restrict__ w0, const float* __restrict__ w1,
              const float* __restrict__ cw1, const float* __restrict__ w2,
              const float* __restrict__ cw2, const float* __restrict__ wo,
              const float* __restrict__ u1_w, const float* __restrict__ u2_w,
              unsigned short* __restrict__ wall, float* __restrict__ p_out) {
    if (blockIdx.x >= 192) {
        const int j = threadIdx.x;
        const int which = blockIdx.x - 192;
        const float* uw = which ? u2_w : u1_w;
        float s = 0.0625f;  // 1/sqrt(256)
#pragma unroll
        for (int d = 0; d < 9; ++d)
#pragma unroll
            for (int g = 0; g < 3; ++g)
                s *= cosf(uw[d * DD * DD + j * DD + g]);
        p_out[which * DD + j] = s * s;
        return;
    }
    const int gid  = blockIdx.x * 256 + threadIdx.x;
    const int mat  = gid >> 13;
    const int rem  = gid & 8191;
    const int wb   = rem >> 11;
    const int rem2 = rem & 2047;
    const int k0   = rem2 >> 8;
    const int rem3 = rem2 & 255;
    const int nt   = rem3 >> 6;
    const int lane = rem3 & 63;
    const int n  = wb * 64 + nt * 16 + (lane & 15);
    const int kb = k0 * 32 + (lane >> 4) * 8;

    const float* src;
    bool tr = false;
    switch (mat) {
        case 0: src = w0; break;
        case 1: src = w1; break;
        case 2: src = cw1; tr = true; break;
        case 3: src = w2; break;
        case 4: src = cw2; tr = true; break;
        default: src = wo; break;
    }
    unsigned short tmp[8];
#pragma unroll
    for (int j = 0; j < 8; ++j) {
        const float v = tr ? src[(kb + j) * DD + n] : src[n * DD + kb + j];
        tmp[j] = f2bf(v);
    }
    *(uint4*)&wall[mat * 65536 + wb * 16384 + k0 * 2048 + nt * 512 + lane * 8] =
        *(const uint4*)tmp;
}

// ---------------------------------------------------------------------------
// LDS activation layout (32 rows): 16 B chunk (m, kc) at kc*32 + (m ^ (kc&7)).
// MFMA frag reads and epilogue writes are bank-conflict-free (verified in the
// original session, R3).
// ---------------------------------------------------------------------------
__device__ __forceinline__ int chunk_idx(int m, int kc) {
    return kc * 32 + (m ^ (kc & 7));
}

__device__ __forceinline__ float fast_tanh(float x) {
    const float e = __expf(2.0f * x);
    return 1.0f - 2.0f * __builtin_amdgcn_rcpf(1.0f + e);
}

// lgkm-only barrier: drains LDS ops for cross-wave visibility but leaves
// global (W-prefetch) loads in flight across the layer boundary.
__device__ __forceinline__ void lds_barrier() {
    asm volatile("s_waitcnt lgkmcnt(0)" ::: "memory");
    __builtin_amdgcn_s_barrier();
}

// ---------------------------------------------------------------------------
// One fused layer, PING-PONG activations (hr -> hw), 32 rows, 4 waves.
// Wave owns 64 n-units (nt=4) x 32 m rows (mt=2).
// Because writes go to the other buffer, NO barrier is needed between the
// MFMA phase and the epilogue -- one wave's epilogue VALU overlaps other
// waves' MFMA. Single lgkm-barrier per layer (writes -> next-layer reads).
// W ring depth 2, slot = k0 & 1; step 7 prefetches next layer's k0=0.
// MODE 0: relu -> hw.  MODE 1: tanh(+p) -> hw.  MODE 2: relu -> direct fp32
// global store (no LDS write, no barrier, skips the bf16 round-trip).
// ---------------------------------------------------------------------------
template <int MODE>
__device__ __forceinline__ void layer_step(const uint4* hr, uint4* hw,
                                           bf16x8 (&wr)[2][4],
                                           const unsigned short* __restrict__ Wb,
                                           const unsigned short* __restrict__ Wnb,
                                           const float* __restrict__ bias,
                                           const float* __restrict__ pv,
                                           float* __restrict__ out, int m0) {
    const int tid  = threadIdx.x;
    const int wave = tid >> 6;
    const int lane = tid & 63;
    const int quad = lane >> 4;
    const int l15  = lane & 15;

    f32x4 acc[4][2];  // [nt][mt]
#pragma unroll
    for (int nt = 0; nt < 4; ++nt)
#pragma unroll
        for (int mt = 0; mt < 2; ++mt) acc[nt][mt] = (f32x4){0.f, 0.f, 0.f, 0.f};

    bf16x8 h_f[2][2];
#pragma unroll
    for (int mt = 0; mt < 2; ++mt)  // k0 = 0 fragments (kc = quad)
        h_f[0][mt] = *(const bf16x8*)&hr[chunk_idx(mt * 16 + l15, quad)];

#pragma unroll
    for (int k0 = 0; k0 < 8; ++k0) {
        const int cur = k0 & 1, nxt = cur ^ 1;
        {  // prefetch next k-step's W frags (next layer's k0=0 at step 7)
            const unsigned short* ws = (k0 < 7) ? &Wb[(k0 + 1) * 2048] : Wnb;
#pragma unroll
            for (int nt = 0; nt < 4; ++nt)
                wr[nxt][nt] = *(const bf16x8*)&ws[nt * 512];
        }
        if (k0 < 7) {
            const int kc = (k0 + 1) * 4 + quad;
#pragma unroll
            for (int mt = 0; mt < 2; ++mt)
                h_f[nxt][mt] = *(const bf16x8*)&hr[chunk_idx(mt * 16 + l15, kc)];
        }
#pragma unroll
        for (int nt = 0; nt < 4; ++nt)
#pragma unroll
            for (int mt = 0; mt < 2; ++mt)
                acc[nt][mt] = __builtin_amdgcn_mfma_f32_16x16x32_bf16(
                    wr[cur][nt], h_f[cur][mt], acc[nt][mt], 0, 0, 0);
    }

    const int nb = wave * 64;
    f32x4 addv[4];
#pragma unroll
    for (int nt = 0; nt < 4; ++nt) {
        const int n0 = nb + nt * 16 + quad * 4;
        addv[nt] = *(const f32x4*)&bias[n0];
        if (MODE == 1) addv[nt] += *(const f32x4*)&pv[n0];
    }

    // NO barrier here: writes go to the other buffer (or global for MODE 2).
#pragma unroll
    for (int nt = 0; nt < 4; ++nt) {
        const int n0   = nb + nt * 16 + quad * 4;
        const int kc_o = n0 >> 3;
        const int half = quad & 1;
#pragma unroll
        for (int mt = 0; mt < 2; ++mt) {
            const f32x4 v = acc[nt][mt] + addv[nt];
            if (MODE == 2) {
                f32x4 r;
                r.x = fmaxf(v.x, 0.f); r.y = fmaxf(v.y, 0.f);
                r.z = fmaxf(v.z, 0.f); r.w = fmaxf(v.w, 0.f);
                *(f32x4*)&out[(size_t)(m0 + mt * 16 + l15) * DD + n0] = r;
            } else {
                float t0, t1, t2, t3;
                if (MODE == 1) {
                    t0 = fast_tanh(v.x); t1 = fast_tanh(v.y);
                    t2 = fast_tanh(v.z); t3 = fast_tanh(v.w);
                } else {
                    t0 = fmaxf(v.x, 0.f); t1 = fmaxf(v.y, 0.f);
                    t2 = fmaxf(v.z, 0.f); t3 = fmaxf(v.w, 0.f);
                }
                uint2 u;
                u.x = (unsigned int)f2bf(t0) | ((unsigned int)f2bf(t1) << 16);
                u.y = (unsigned int)f2bf(t2) | ((unsigned int)f2bf(t3) << 16);
                *(uint2*)((char*)&hw[chunk_idx(mt * 16 + l15, kc_o)] + half * 8) = u;
            }
        }
    }
    if (MODE != 2) lds_barrier();  // writes visible for next layer
}

__global__ __launch_bounds__(256, 4)
void unet_fused(const float* __restrict__ x,
                const unsigned short* __restrict__ wall,
                const float* __restrict__ b0, const float* __restrict__ b1,
                const float* __restrict__ cb1, const float* __restrict__ b2,
                const float* __restrict__ cb2, const float* __restrict__ bo,
                const float* __restrict__ pbuf,
                float* __restrict__ out) {
    __shared__ uint4 hbuf[2048];  // 2 x 16 KB ping-pong: 32 rows x 256 bf16
    uint4* hA = hbuf;
    uint4* hB = hbuf + 1024;
    const int m0   = blockIdx.x * 32;
    const int tid  = threadIdx.x;
    const int wave = tid >> 6;
    const int lane = tid & 63;

    // this wave's fragment base inside any W matrix
    const unsigned short* WB = wall + wave * 16384 + lane * 8;

    // prime W ring slot 0 with layer-0 k0=0 BEFORE x staging (latency overlap)
    bf16x8 wr[2][4];
#pragma unroll
    for (int nt = 0; nt < 4; ++nt)
        wr[0][nt] = *(const bf16x8*)&WB[nt * 512];

    // stage x (fp32, coalesced reads) -> hA (bf16 chunks)
    const int c4     = tid & 63;  // float4 column index (k = c4*4)
    const int rbase  = wave * 8;
    const int kc_s   = c4 >> 1;
    const int half_s = c4 & 1;
#pragma unroll
    for (int i = 0; i < 8; ++i) {
        const int row = rbase + i;
        const float4 v = *(const float4*)&x[(size_t)(m0 + row) * DD + c4 * 4];
        uint2 u;
        u.x = (unsigned int)f2bf(v.x) | ((unsigned int)f2bf(v.y) << 16);
        u.y = (unsigned int)f2bf(v.z) | ((unsigned int)f2bf(v.w) << 16);
        *(uint2*)((char*)&hA[chunk_idx(row, kc_s)] + half_s * 8) = u;
    }
    lds_barrier();

    layer_step<0>(hA, hB, wr, WB + 0 * 65536, WB + 1 * 65536, b0, nullptr,
                  nullptr, 0);
    layer_step<0>(hB, hA, wr, WB + 1 * 65536, WB + 2 * 65536, b1, nullptr,
                  nullptr, 0);
    layer_step<1>(hA, hB, wr, WB + 2 * 65536, WB + 3 * 65536, cb1, pbuf,
                  nullptr, 0);
    layer_step<0>(hB, hA, wr, WB + 3 * 65536, WB + 4 * 65536, b2, nullptr,
                  nullptr, 0);
    layer_step<1>(hA, hB, wr, WB + 4 * 65536, WB + 5 * 65536, cb2, pbuf + 256,
                  nullptr, 0);
    // final layer: relu + direct fp32 stores (no LDS round-trip, no barrier)
    layer_step<2>(hB, nullptr, wr, WB + 5 * 65536, WB + 0 * 65536, bo, nullptr,
                  out, m0);
}

// ---------------------------------------------------------------------------
extern "C" void kernel_launch(void* const* d_in, const int* in_sizes, int n_in,
                              void* d_out, int out_size, void* d_ws, size_t ws_size,
                              hipStream_t stream) {
    const float* x      = (const float*)d_in[0];
    const float* lin0_w = (const float*)d_in[1];
    const float* lin0_b = (const float*)d_in[2];
    const float* lin1_w = (const float*)d_in[3];
    const float* lin1_b = (const float*)d_in[4];
    const float* u1_w   = (const float*)d_in[5];
    const float* u1_cw  = (const float*)d_in[6];
    const float* u1_cb  = (const float*)d_in[7];
    const float* lin2_w = (const float*)d_in[8];
    const float* lin2_b = (const float*)d_in[9];
    const float* u2_w   = (const float*)d_in[10];
    const float* u2_cw  = (const float*)d_in[11];
    const float* u2_cb  = (const float*)d_in[12];
    const float* lino_w = (const float*)d_in[13];
    const float* lino_b = (const float*)d_in[14];

    float* out = (float*)d_out;
    unsigned short* wall = (unsigned short*)d_ws;         // 6*65536 bf16 = 768 KB
    float* pbuf = (float*)((char*)d_ws + 6 * 65536 * 2);  // 512 floats

    prep_all<<<dim3(194), dim3(256), 0, stream>>>(
        lin0_w, lin1_w, u1_cw, lin2_w, u2_cw, lino_w, u1_w, u2_w, wall, pbuf);
    unet_fused<<<dim3(1024), dim3(256), 0, stream>>>(
        x, wall, lin0_b, lin1_b, u1_cb, lin2_b, u2_cb, lino_b, pbuf, out);
}

// Round 3
// 149.793 us; speedup vs baseline: 1.0547x; 1.0547x over previous
//
#include <hip/hip_runtime.h>
#include <math.h>

#define DD 256

typedef float  f32x4  __attribute__((ext_vector_type(4)));
typedef short  bf16x8 __attribute__((ext_vector_type(8)));

__device__ __forceinline__ unsigned short f2bf(float f) {
    unsigned int u = __float_as_uint(f);
    u = (u + 0x7fffu + ((u >> 16) & 1u)) >> 16;  // RNE
    return (unsigned short)u;
}
__device__ __forceinline__ float bf2f(unsigned int h16) {
    return __uint_as_float(h16 << 16);
}

// ---------------------------------------------------------------------------
// Fused prep: blocks [0,192) repack weights fp32->bf16 into MFMA-fragment-
// linear order:
//   wall[mat][wb][k0][nt][lane] : 16 B holding
//   W_bt[n = wb*64 + nt*16 + (lane&15)][k = k0*32 + (lane>>4)*8 .. +8]
// Blocks 192,193 compute the universal-layer p vectors (uniform state is
// preserved by the circulant update -> s0 = 0.0625*prod cos; verified earlier).
// ---------------------------------------------------------------------------
__global__ __launch_bounds__(256)
void prep_all(const float* __restrict__ w0, const float* __restrict__ w1,
              const float* __restrict__ cw1, const float* __restrict__ w2,
              const float* __restrict__ cw2, const float* __restrict__ wo,
              const float* __restrict__ u1_w, const float* __restrict__ u2_w,
              unsigned short* __restrict__ wall, float* __restrict__ p_out) {
    if (blockIdx.x >= 192) {
        const int j = threadIdx.x;
        const int which = blockIdx.x - 192;
        const float* uw = which ? u2_w : u1_w;
        float s = 0.0625f;  // 1/sqrt(256)
#pragma unroll
        for (int d = 0; d < 9; ++d)
#pragma unroll
            for (int g = 0; g < 3; ++g)
                s *= cosf(uw[d * DD * DD + j * DD + g]);
        p_out[which * DD + j] = s * s;
        return;
    }
    const int gid  = blockIdx.x * 256 + threadIdx.x;
    const int mat  = gid >> 13;
    const int rem  = gid & 8191;
    const int wb   = rem >> 11;
    const int rem2 = rem & 2047;
    const int k0   = rem2 >> 8;
    const int rem3 = rem2 & 255;
    const int nt   = rem3 >> 6;
    const int lane = rem3 & 63;
    const int n  = wb * 64 + nt * 16 + (lane & 15);
    const int kb = k0 * 32 + (lane >> 4) * 8;

    const float* src;
    bool tr = false;
    switch (mat) {
        case 0: src = w0; break;
        case 1: src = w1; break;
        case 2: src = cw1; tr = true; break;
        case 3: src = w2; break;
        case 4: src = cw2; tr = true; break;
        default: src = wo; break;
    }
    unsigned short tmp[8];
#pragma unroll
    for (int j = 0; j < 8; ++j) {
        const float v = tr ? src[(kb + j) * DD + n] : src[n * DD + kb + j];
        tmp[j] = f2bf(v);
    }
    *(uint4*)&wall[mat * 65536 + wb * 16384 + k0 * 2048 + nt * 512 + lane * 8] =
        *(const uint4*)tmp;
}

// ---------------------------------------------------------------------------
// LDS activation layout (32 rows): 16 B chunk (m, kc) at kc*32 + (m ^ (kc&7)).
// MFMA frag reads and epilogue writes are bank-conflict-free (verified).
// ---------------------------------------------------------------------------
__device__ __forceinline__ int chunk_idx(int m, int kc) {
    return kc * 32 + (m ^ (kc & 7));
}

__device__ __forceinline__ float fast_tanh(float x) {
    const float e = __expf(2.0f * x);
    return 1.0f - 2.0f * __builtin_amdgcn_rcpf(1.0f + e);
}

// ---------------------------------------------------------------------------
// One fused layer, in-place activations, 32 rows, 4 waves (R0 geometry —
// the proven 50 µs base). ONE structural change vs R0: W ring depth 4,
// prefetch distance 3 (lead ~3 steps >= L2 latency; depth-2's 1-step lead
// stalled every step). 8 steps % 4 == 0 so slot phase is layer-invariant;
// steps 5..7 prefetch the next layer's k0 = 0..2, completing under the
// epilogue + barriers.
// Barriers are plain __syncthreads(): the lgkm-only asm barrier regressed
// ~16% in BOTH R1 and R2 — hipcc schedules better around its own barrier.
// MODE 0: relu -> h.  MODE 1: tanh(+p) -> h.  MODE 2: relu -> direct fp32
// global store (no LDS write, no barriers, skips the bf16 round-trip).
// ---------------------------------------------------------------------------
template <int MODE>
__device__ __forceinline__ void layer_step(uint4* h, bf16x8 (&wr)[4][4],
                                           const unsigned short* __restrict__ Wb,
                                           const unsigned short* __restrict__ Wnb,
                                           const float* __restrict__ bias,
                                           const float* __restrict__ pv,
                                           float* __restrict__ out, int m0) {
    const int tid  = threadIdx.x;
    const int wave = tid >> 6;
    const int lane = tid & 63;
    const int quad = lane >> 4;
    const int l15  = lane & 15;

    f32x4 acc[4][2];  // [nt][mt]
#pragma unroll
    for (int nt = 0; nt < 4; ++nt)
#pragma unroll
        for (int mt = 0; mt < 2; ++mt) acc[nt][mt] = (f32x4){0.f, 0.f, 0.f, 0.f};

    bf16x8 h_f[2][2];
#pragma unroll
    for (int mt = 0; mt < 2; ++mt)  // k0 = 0 fragments (kc = quad)
        h_f[0][mt] = *(const bf16x8*)&h[chunk_idx(mt * 16 + l15, quad)];

#pragma unroll
    for (int k0 = 0; k0 < 8; ++k0) {
        {   // prefetch W frags for step k0+3 (ring depth 4, distance 3)
            const int t = k0 + 3;
            const unsigned short* ws = (t < 8) ? &Wb[t * 2048] : &Wnb[(t - 8) * 2048];
#pragma unroll
            for (int nt = 0; nt < 4; ++nt)
                wr[t & 3][nt] = *(const bf16x8*)&ws[nt * 512];
        }
        if (k0 < 7) {
            const int kc = (k0 + 1) * 4 + quad;
#pragma unroll
            for (int mt = 0; mt < 2; ++mt)
                h_f[(k0 + 1) & 1][mt] = *(const bf16x8*)&h[chunk_idx(mt * 16 + l15, kc)];
        }
#pragma unroll
        for (int nt = 0; nt < 4; ++nt)
#pragma unroll
            for (int mt = 0; mt < 2; ++mt)
                acc[nt][mt] = __builtin_amdgcn_mfma_f32_16x16x32_bf16(
                    wr[k0 & 3][nt], h_f[k0 & 1][mt], acc[nt][mt], 0, 0, 0);
    }

    // bias (+p) fetch issued before the barrier so latency hides under it
    const int nb = wave * 64;
    f32x4 addv[4];
#pragma unroll
    for (int nt = 0; nt < 4; ++nt) {
        const int n0 = nb + nt * 16 + quad * 4;
        addv[nt] = *(const f32x4*)&bias[n0];
        if (MODE == 1) addv[nt] += *(const f32x4*)&pv[n0];
    }

    if (MODE != 2) __syncthreads();  // all reads of h done -> safe to overwrite

#pragma unroll
    for (int nt = 0; nt < 4; ++nt) {
        const int n0   = nb + nt * 16 + quad * 4;
        const int kc_o = n0 >> 3;
        const int half = quad & 1;
#pragma unroll
        for (int mt = 0; mt < 2; ++mt) {
            const f32x4 v = acc[nt][mt] + addv[nt];
            if (MODE == 2) {
                f32x4 r;
                r.x = fmaxf(v.x, 0.f); r.y = fmaxf(v.y, 0.f);
                r.z = fmaxf(v.z, 0.f); r.w = fmaxf(v.w, 0.f);
                *(f32x4*)&out[(size_t)(m0 + mt * 16 + l15) * DD + n0] = r;
            } else {
                float t0, t1, t2, t3;
                if (MODE == 1) {
                    t0 = fast_tanh(v.x); t1 = fast_tanh(v.y);
                    t2 = fast_tanh(v.z); t3 = fast_tanh(v.w);
                } else {
                    t0 = fmaxf(v.x, 0.f); t1 = fmaxf(v.y, 0.f);
                    t2 = fmaxf(v.z, 0.f); t3 = fmaxf(v.w, 0.f);
                }
                uint2 u;
                u.x = (unsigned int)f2bf(t0) | ((unsigned int)f2bf(t1) << 16);
                u.y = (unsigned int)f2bf(t2) | ((unsigned int)f2bf(t3) << 16);
                *(uint2*)((char*)&h[chunk_idx(mt * 16 + l15, kc_o)] + half * 8) = u;
            }
        }
    }
    if (MODE != 2) __syncthreads();  // writes visible for next layer
}

__global__ __launch_bounds__(256, 4)
void unet_fused(const float* __restrict__ x,
                const unsigned short* __restrict__ wall,
                const float* __restrict__ b0, const float* __restrict__ b1,
                const float* __restrict__ cb1, const float* __restrict__ b2,
                const float* __restrict__ cb2, const float* __restrict__ bo,
                const float* __restrict__ pbuf,
                float* __restrict__ out) {
    __shared__ uint4 h[1024];  // 16 KB: 32 rows x 256 bf16, chunked+swizzled
    const int m0   = blockIdx.x * 32;
    const int tid  = threadIdx.x;
    const int wave = tid >> 6;
    const int lane = tid & 63;

    // this wave's fragment base inside any W matrix
    const unsigned short* WB = wall + wave * 16384 + lane * 8;

    // prime W ring slots 0..2 with layer-0 steps 0..2 BEFORE x staging
    // (their latency hides under the fp32 x loads + LDS staging + barrier)
    bf16x8 wr[4][4];
#pragma unroll
    for (int t = 0; t < 3; ++t)
#pragma unroll
        for (int nt = 0; nt < 4; ++nt)
            wr[t][nt] = *(const bf16x8*)&WB[t * 2048 + nt * 512];

    // stage x (fp32, coalesced reads) -> h (bf16 chunks)
    const int c4     = tid & 63;  // float4 column index (k = c4*4)
    const int rbase  = wave * 8;
    const int kc_s   = c4 >> 1;
    const int half_s = c4 & 1;
#pragma unroll
    for (int i = 0; i < 8; ++i) {
        const int row = rbase + i;
        const float4 v = *(const float4*)&x[(size_t)(m0 + row) * DD + c4 * 4];
        uint2 u;
        u.x = (unsigned int)f2bf(v.x) | ((unsigned int)f2bf(v.y) << 16);
        u.y = (unsigned int)f2bf(v.z) | ((unsigned int)f2bf(v.w) << 16);
        *(uint2*)((char*)&h[chunk_idx(row, kc_s)] + half_s * 8) = u;
    }
    __syncthreads();

    layer_step<0>(h, wr, WB + 0 * 65536, WB + 1 * 65536, b0, nullptr,
                  nullptr, 0);
    layer_step<0>(h, wr, WB + 1 * 65536, WB + 2 * 65536, b1, nullptr,
                  nullptr, 0);
    layer_step<1>(h, wr, WB + 2 * 65536, WB + 3 * 65536, cb1, pbuf,
                  nullptr, 0);
    layer_step<0>(h, wr, WB + 3 * 65536, WB + 4 * 65536, b2, nullptr,
                  nullptr, 0);
    layer_step<1>(h, wr, WB + 4 * 65536, WB + 5 * 65536, cb2, pbuf + 256,
                  nullptr, 0);
    // final layer: relu + direct fp32 stores (no LDS round-trip, no barrier)
    layer_step<2>(h, wr, WB + 5 * 65536, WB + 0 * 65536, bo, nullptr,
                  out, m0);
}

// ---------------------------------------------------------------------------
extern "C" void kernel_launch(void* const* d_in, const int* in_sizes, int n_in,
                              void* d_out, int out_size, void* d_ws, size_t ws_size,
                              hipStream_t stream) {
    const float* x      = (const float*)d_in[0];
    const float* lin0_w = (const float*)d_in[1];
    const float* lin0_b = (const float*)d_in[2];
    const float* lin1_w = (const float*)d_in[3];
    const float* lin1_b = (const float*)d_in[4];
    const float* u1_w   = (const float*)d_in[5];
    const float* u1_cw  = (const float*)d_in[6];
    const float* u1_cb  = (const float*)d_in[7];
    const float* lin2_w = (const float*)d_in[8];
    const float* lin2_b = (const float*)d_in[9];
    const float* u2_w   = (const float*)d_in[10];
    const float* u2_cw  = (const float*)d_in[11];
    const float* u2_cb  = (const float*)d_in[12];
    const float* lino_w = (const float*)d_in[13];
    const float* lino_b = (const float*)d_in[14];

    float* out = (float*)d_out;
    unsigned short* wall = (unsigned short*)d_ws;         // 6*65536 bf16 = 768 KB
    float* pbuf = (float*)((char*)d_ws + 6 * 65536 * 2);  // 512 floats

    prep_all<<<dim3(194), dim3(256), 0, stream>>>(
        lin0_w, lin1_w, u1_cw, lin2_w, u2_cw, lino_w, u1_w, u2_w, wall, pbuf);
    unet_fused<<<dim3(1024), dim3(256), 0, stream>>>(
        x, wall, lin0_b, lin1_b, u1_cb, lin2_b, u2_cb, lino_b, pbuf, out);
}